// Round 1
// baseline (568.373 us; speedup 1.0000x reference)
//
#include <hip/hip_runtime.h>
#include <math.h>

#define B 2
#define M 1024
#define V 300
#define C 128
#define HID 128
#define BIN 256
#define H 384
#define W 512
#define QIN (C + 7)   // 135

// ---------------------------------------------------------------------------
// Kernel 1: anchor MLP  a[v,:] = relu(vd@Wa1+ba1)@Wa2+ba2   (V x HID)
//           bias[v]    = (relu(vd@Wb1+bb1)@Wb2+bb2)[0]      (V)
// One block per view, 128 threads.
// ---------------------------------------------------------------------------
__global__ __launch_bounds__(HID) void anchor_kernel(
    const float* __restrict__ view_dirs,
    const float* __restrict__ Wa1, const float* __restrict__ ba1,
    const float* __restrict__ Wa2, const float* __restrict__ ba2,
    const float* __restrict__ Wb1, const float* __restrict__ bb1,
    const float* __restrict__ Wb2, const float* __restrict__ bb2,
    float* __restrict__ a_out, float* __restrict__ bias_out) {
  const int v = blockIdx.x;
  const int t = threadIdx.x;
  __shared__ float h1[HID];
  __shared__ float hb[HID / 2];

  const float vd0 = view_dirs[v * 3 + 0];
  const float vd1 = view_dirs[v * 3 + 1];
  const float vd2 = view_dirs[v * 3 + 2];

  float h = vd0 * Wa1[0 * HID + t] + vd1 * Wa1[1 * HID + t] + vd2 * Wa1[2 * HID + t] + ba1[t];
  h1[t] = fmaxf(h, 0.0f);
  if (t < HID / 2) {
    float x = vd0 * Wb1[0 * 64 + t] + vd1 * Wb1[1 * 64 + t] + vd2 * Wb1[2 * 64 + t] + bb1[t];
    hb[t] = fmaxf(x, 0.0f);
  }
  __syncthreads();

  float acc = ba2[t];
#pragma unroll 8
  for (int k = 0; k < HID; ++k) acc += h1[k] * Wa2[k * HID + t];
  a_out[v * HID + t] = acc;

  if (t == 0) {
    float bacc = bb2[0];
    for (int k = 0; k < 64; ++k) bacc += hb[k] * Wb2[k];
    bias_out[v] = bacc;
  }
}

// ---------------------------------------------------------------------------
// Kernel 2: one block per seed (b,m), 128 threads.
//   gather geometry (entropy over 256 bins, central-diff normal, ray)
//   -> q MLP -> logits vs all 300 anchors -> sigmoid/argmax -> outputs
//   -> residual MLP.
// ---------------------------------------------------------------------------
__global__ __launch_bounds__(128) void seed_kernel(
    const float* __restrict__ seed_features, const int* __restrict__ token_sel_idx,
    const float* __restrict__ Kmat, const float* __restrict__ depth_map,
    const float* __restrict__ depth_prob, const float* __restrict__ view_dirs,
    const float* __restrict__ Wq1, const float* __restrict__ bq1,
    const float* __restrict__ Wq2, const float* __restrict__ bq2,
    const float* __restrict__ Wr1, const float* __restrict__ br1,
    const float* __restrict__ Wr2, const float* __restrict__ br2,
    const float* __restrict__ a_ws, const float* __restrict__ bias_ws,
    float* __restrict__ out_view_score, float* __restrict__ out_top_inds,
    float* __restrict__ out_top_xyz, float* __restrict__ out_rot,
    float* __restrict__ out_res) {
  const int bm = blockIdx.x;
  const int b = bm / M;
  const int m = bm - b * M;
  const int t = threadIdx.x;

  __shared__ float qin_s[QIN + 1];
  __shared__ float hs[HID];
  __shared__ float qs[HID];
  __shared__ float red_v[128];
  __shared__ int   red_i[128];
  __shared__ float atop_s[HID];

  // ---- seed features (gather column m) ----
  qin_s[t] = seed_features[((size_t)b * C + t) * M + m];

  const int idx = token_sel_idx[b * M + m];

  // ---- entropy over 256 bins (2 bins per thread, tree-reduce) ----
  {
    const float* dp = depth_prob + (size_t)b * BIN * H * W + idx;
    float p0 = fmaxf(dp[(size_t)(2 * t + 0) * (H * W)], 1e-8f);
    float p1 = fmaxf(dp[(size_t)(2 * t + 1) * (H * W)], 1e-8f);
    red_v[t] = p0 * logf(p0) + p1 * logf(p1);
  }
  __syncthreads();
  for (int s = 64; s > 0; s >>= 1) {
    if (t < s) red_v[t] += red_v[t + s];
    __syncthreads();
  }

  // ---- thread 0: uncertainty, normal, ray -> qin_s[128..134] ----
  if (t == 0) {
    float uncert = (-red_v[0]) / 5.5451774444795623f;  // log(256)
    uncert = fminf(fmaxf(uncert, 0.0f), 1.0f);

    const float fx = Kmat[b * 9 + 0], fy = Kmat[b * 9 + 4];
    const float cx = Kmat[b * 9 + 2], cy = Kmat[b * 9 + 5];
    const int w = idx % W;
    const int h = idx / W;
    const int hc = min(max(h, 1), H - 2);
    const int wc = min(max(w, 1), W - 2);

    const float* dm = depth_map + (size_t)b * H * W;
    const float zl = dm[hc * W + (wc - 1)];
    const float zr = dm[hc * W + (wc + 1)];
    const float zu = dm[(hc - 1) * W + wc];
    const float zd = dm[(hc + 1) * W + wc];

    // dx = xyz(hc, wc+1) - xyz(hc, wc-1)
    const float dxx = (wc + 1 - cx) / fx * zr - (wc - 1 - cx) / fx * zl;
    const float dxy = (hc - cy) / fy * zr - (hc - cy) / fy * zl;
    const float dxz = zr - zl;
    // dy = xyz(hc+1, wc) - xyz(hc-1, wc)
    const float dyx = (wc - cx) / fx * zd - (wc - cx) / fx * zu;
    const float dyy = (hc + 1 - cy) / fy * zd - (hc - 1 - cy) / fy * zu;
    const float dyz = zd - zu;

    float nx = dxy * dyz - dxz * dyy;
    float ny = dxz * dyx - dxx * dyz;
    float nz = dxx * dyy - dxy * dyx;
    const float nn = fmaxf(sqrtf(nx * nx + ny * ny + nz * nz), 1e-6f);
    const float sc = (1.0f - uncert) / nn;

    const float rx = ((float)w - cx) / fx;
    const float ry = ((float)h - cy) / fy;
    const float rn = fmaxf(sqrtf(rx * rx + ry * ry + 1.0f), 1e-12f);

    qin_s[128] = rx / rn;
    qin_s[129] = ry / rn;
    qin_s[130] = 1.0f / rn;
    qin_s[131] = nx * sc;
    qin_s[132] = ny * sc;
    qin_s[133] = nz * sc;
    qin_s[134] = uncert;
  }
  __syncthreads();

  // ---- q MLP: thread t owns output column t ----
  float acc = bq1[t];
#pragma unroll 5
  for (int i = 0; i < QIN; ++i) acc += qin_s[i] * Wq1[i * HID + t];
  hs[t] = fmaxf(acc, 0.0f);
  __syncthreads();

  acc = bq2[t];
#pragma unroll 8
  for (int k = 0; k < HID; ++k) acc += hs[k] * Wq2[k * HID + t];
  qs[t] = fmaxf(acc, 0.0f);
  __syncthreads();

  // ---- logits vs all V anchors; sigmoid + argmax (first-index ties) ----
  float bestv = -1.0f;
  int besti = 0;
  float* vs_out = out_view_score + (size_t)bm * V;
  for (int v = t; v < V; v += 128) {
    const float* av = a_ws + v * HID;
    float dot = 0.0f;
#pragma unroll 8
    for (int k = 0; k < HID; ++k) dot += qs[k] * av[k];
    const float logit = dot / sqrtf((float)HID) + bias_ws[v];
    const float scv = 1.0f / (1.0f + expf(-logit));
    vs_out[v] = scv;
    if (scv > bestv) { bestv = scv; besti = v; }  // v ascending -> first-index ties
  }
  red_v[t] = bestv;
  red_i[t] = besti;
  __syncthreads();
  for (int s = 64; s > 0; s >>= 1) {
    if (t < s) {
      const float ov = red_v[t + s];
      const int oi = red_i[t + s];
      if (ov > red_v[t] || (ov == red_v[t] && oi < red_i[t])) {
        red_v[t] = ov;
        red_i[t] = oi;
      }
    }
    __syncthreads();
  }
  const int best = red_i[0];

  // ---- top outputs (thread 0) ----
  if (t == 0) {
    out_top_inds[bm] = (float)best;
    const float vx = view_dirs[best * 3 + 0];
    const float vy = view_dirs[best * 3 + 1];
    const float vz = view_dirs[best * 3 + 2];
    out_top_xyz[(size_t)bm * 3 + 0] = vx;
    out_top_xyz[(size_t)bm * 3 + 1] = vy;
    out_top_xyz[(size_t)bm * 3 + 2] = vz;

    // rot: axis_x=-v; axis_y=(vy,-vx,0) normalized (fallback (0,1,0)); axis_z=cross
    float ax0 = -vx, ax1 = -vy, ax2 = -vz;
    float ay0 = vy, ay1 = -vx, ay2 = 0.0f;
    const float nyn = sqrtf(ay0 * ay0 + ay1 * ay1);
    if (nyn < 1e-8f) {
      ay0 = 0.0f; ay1 = 1.0f; ay2 = 0.0f;
    } else {
      const float d = fmaxf(nyn, 1e-8f);
      ay0 /= d; ay1 /= d;
    }
    const float an = fmaxf(sqrtf(ax0 * ax0 + ax1 * ax1 + ax2 * ax2), 1e-8f);
    ax0 /= an; ax1 /= an; ax2 /= an;
    const float az0 = ax1 * ay2 - ax2 * ay1;
    const float az1 = ax2 * ay0 - ax0 * ay2;
    const float az2 = ax0 * ay1 - ax1 * ay0;
    float* R = out_rot + (size_t)bm * 9;
    R[0] = ax0; R[1] = ay0; R[2] = az0;
    R[3] = ax1; R[4] = ay1; R[5] = az1;
    R[6] = ax2; R[7] = ay2; R[8] = az2;
  }

  // ---- residual MLP: res = relu((q + a_top)@Wr1 + br1)@Wr2 + br2 ----
  atop_s[t] = a_ws[best * HID + t];
  __syncthreads();

  float racc = br1[t];
#pragma unroll 8
  for (int k = 0; k < HID; ++k) racc += (qs[k] + atop_s[k]) * Wr1[k * HID + t];
  hs[t] = fmaxf(racc, 0.0f);
  __syncthreads();

  racc = br2[t];
#pragma unroll 8
  for (int k = 0; k < HID; ++k) racc += hs[k] * Wr2[k * HID + t];
  out_res[((size_t)b * C + t) * M + m] = racc;
}

// ---------------------------------------------------------------------------
extern "C" void kernel_launch(void* const* d_in, const int* in_sizes, int n_in,
                              void* d_out, int out_size, void* d_ws, size_t ws_size,
                              hipStream_t stream) {
  const float* seed  = (const float*)d_in[0];
  const int*   tok   = (const int*)d_in[1];
  const float* Km    = (const float*)d_in[2];
  const float* dmap  = (const float*)d_in[3];
  const float* dprob = (const float*)d_in[4];
  const float* vdirs = (const float*)d_in[5];
  const float* Wq1 = (const float*)d_in[6];  const float* bq1 = (const float*)d_in[7];
  const float* Wq2 = (const float*)d_in[8];  const float* bq2 = (const float*)d_in[9];
  const float* Wa1 = (const float*)d_in[10]; const float* ba1 = (const float*)d_in[11];
  const float* Wa2 = (const float*)d_in[12]; const float* ba2 = (const float*)d_in[13];
  const float* Wb1 = (const float*)d_in[14]; const float* bb1 = (const float*)d_in[15];
  const float* Wb2 = (const float*)d_in[16]; const float* bb2 = (const float*)d_in[17];
  const float* Wr1 = (const float*)d_in[18]; const float* br1 = (const float*)d_in[19];
  const float* Wr2 = (const float*)d_in[20]; const float* br2 = (const float*)d_in[21];

  float* out = (float*)d_out;
  float* vs  = out;                                  // view_score (B,M,V)
  float* ti  = vs + (size_t)B * M * V;               // top_inds  (B,M) as float
  float* tx  = ti + (size_t)B * M;                   // top_xyz   (B,M,3)
  float* rot = tx + (size_t)B * M * 3;               // rot       (B,M,3,3)
  float* rf  = rot + (size_t)B * M * 9;              // res_feat  (B,C,M)

  float* a_ws    = (float*)d_ws;                     // V*HID
  float* bias_ws = a_ws + (size_t)V * HID;           // V

  anchor_kernel<<<V, HID, 0, stream>>>(vdirs, Wa1, ba1, Wa2, ba2, Wb1, bb1, Wb2, bb2,
                                       a_ws, bias_ws);
  seed_kernel<<<B * M, 128, 0, stream>>>(seed, tok, Km, dmap, dprob, vdirs,
                                         Wq1, bq1, Wq2, bq2, Wr1, br1, Wr2, br2,
                                         a_ws, bias_ws, vs, ti, tx, rot, rf);
}

// Round 2
// 550.329 us; speedup vs baseline: 1.0328x; 1.0328x over previous
//
#include <hip/hip_runtime.h>
#include <math.h>

#define B 2
#define M 1024
#define V 300
#define C 128
#define HID 128
#define BIN 256
#define H 384
#define W 512
#define QIN (C + 7)   // 135

// ---------------------------------------------------------------------------
// Kernel 0: transpose seed_features (B,C,M) -> seedT (B,M,C), 32x32 LDS tiles.
// grid (C/32, M/32, B), block (32,4).
// ---------------------------------------------------------------------------
__global__ __launch_bounds__(128) void transpose_seed(
    const float* __restrict__ in, float* __restrict__ out) {
  __shared__ float tile[32][33];
  const int b  = blockIdx.z;
  const int c0 = blockIdx.x * 32;
  const int m0 = blockIdx.y * 32;
  const int tx = threadIdx.x;
#pragma unroll
  for (int r = threadIdx.y; r < 32; r += 4)
    tile[r][tx] = in[((size_t)b * C + c0 + r) * M + m0 + tx];
  __syncthreads();
#pragma unroll
  for (int r = threadIdx.y; r < 32; r += 4)
    out[((size_t)b * M + m0 + r) * C + c0 + tx] = tile[tx][r];
}

// ---------------------------------------------------------------------------
// Kernel 1: anchor MLP  a[v,:]=relu(vd@Wa1+ba1)@Wa2+ba2  -> a_ws (VxHID) and
//           aT_ws (HIDxV);  bias[v]=(relu(vd@Wb1+bb1)@Wb2+bb2)[0].
// One block per view, 128 threads.
// ---------------------------------------------------------------------------
__global__ __launch_bounds__(HID) void anchor_kernel(
    const float* __restrict__ view_dirs,
    const float* __restrict__ Wa1, const float* __restrict__ ba1,
    const float* __restrict__ Wa2, const float* __restrict__ ba2,
    const float* __restrict__ Wb1, const float* __restrict__ bb1,
    const float* __restrict__ Wb2, const float* __restrict__ bb2,
    float* __restrict__ a_out, float* __restrict__ aT_out,
    float* __restrict__ bias_out) {
  const int v = blockIdx.x;
  const int t = threadIdx.x;
  __shared__ float h1[HID];

  const float vd0 = view_dirs[v * 3 + 0];
  const float vd1 = view_dirs[v * 3 + 1];
  const float vd2 = view_dirs[v * 3 + 2];

  float h = vd0 * Wa1[0 * HID + t] + vd1 * Wa1[1 * HID + t] + vd2 * Wa1[2 * HID + t] + ba1[t];
  h1[t] = fmaxf(h, 0.0f);

  // bias head: wave 0 (lanes 0..63) shuffle-reduce
  if (t < 64) {
    float x = vd0 * Wb1[0 * 64 + t] + vd1 * Wb1[1 * 64 + t] + vd2 * Wb1[2 * 64 + t] + bb1[t];
    x = fmaxf(x, 0.0f) * Wb2[t];
#pragma unroll
    for (int o = 32; o > 0; o >>= 1) x += __shfl_down(x, o, 64);
    if (t == 0) bias_out[v] = x + bb2[0];
  }
  __syncthreads();

  float acc = ba2[t];
#pragma unroll 8
  for (int k = 0; k < HID; ++k) acc += h1[k] * Wa2[k * HID + t];
  a_out[v * HID + t] = acc;
  aT_out[(size_t)t * V + v] = acc;
}

// ---------------------------------------------------------------------------
// Kernel 2: one block per seed (b,m), 128 threads.
// ---------------------------------------------------------------------------
__global__ __launch_bounds__(128) void seed_kernel(
    const float* __restrict__ seedT, const int* __restrict__ token_sel_idx,
    const float* __restrict__ Kmat, const float* __restrict__ depth_map,
    const float* __restrict__ depth_prob, const float* __restrict__ view_dirs,
    const float* __restrict__ Wq1, const float* __restrict__ bq1,
    const float* __restrict__ Wq2, const float* __restrict__ bq2,
    const float* __restrict__ Wr1, const float* __restrict__ br1,
    const float* __restrict__ Wr2, const float* __restrict__ br2,
    const float* __restrict__ a_ws, const float* __restrict__ aT_ws,
    const float* __restrict__ bias_ws,
    float* __restrict__ out_view_score, float* __restrict__ out_top_inds,
    float* __restrict__ out_top_xyz, float* __restrict__ out_rot,
    float* __restrict__ out_res) {
  const int bm = blockIdx.x;
  const int b = bm / M;
  const int m = bm - b * M;
  const int t = threadIdx.x;
  const int lane = t & 63;
  const int wv = t >> 6;

  __shared__ float qin_s[QIN + 1];
  __shared__ float hs[HID];
  __shared__ float qs[HID];
  __shared__ float atop_s[HID];
  __shared__ float ered[2];
  __shared__ float wbv[2];
  __shared__ int   wbi[2];
  __shared__ int   sbest;

  // ---- seed features: coalesced row read from transposed copy ----
  qin_s[t] = seedT[((size_t)b * M + m) * C + t];

  const int idx = token_sel_idx[b * M + m];

  // ---- entropy over 256 bins (2/thread, wave shuffle reduce) ----
  {
    const float* dp = depth_prob + (size_t)b * BIN * H * W + idx;
    float p0 = fmaxf(dp[(size_t)(2 * t + 0) * (H * W)], 1e-8f);
    float p1 = fmaxf(dp[(size_t)(2 * t + 1) * (H * W)], 1e-8f);
    float e = p0 * logf(p0) + p1 * logf(p1);
#pragma unroll
    for (int o = 32; o > 0; o >>= 1) e += __shfl_down(e, o, 64);
    if (lane == 0) ered[wv] = e;
  }
  __syncthreads();

  // ---- thread 0: uncertainty, normal, ray -> qin_s[128..134] ----
  if (t == 0) {
    float uncert = (-(ered[0] + ered[1])) / 5.5451774444795623f;  // log(256)
    uncert = fminf(fmaxf(uncert, 0.0f), 1.0f);

    const float fx = Kmat[b * 9 + 0], fy = Kmat[b * 9 + 4];
    const float cx = Kmat[b * 9 + 2], cy = Kmat[b * 9 + 5];
    const int w = idx % W;
    const int h = idx / W;
    const int hc = min(max(h, 1), H - 2);
    const int wc = min(max(w, 1), W - 2);

    const float* dm = depth_map + (size_t)b * H * W;
    const float zl = dm[hc * W + (wc - 1)];
    const float zr = dm[hc * W + (wc + 1)];
    const float zu = dm[(hc - 1) * W + wc];
    const float zd = dm[(hc + 1) * W + wc];

    const float dxx = (wc + 1 - cx) / fx * zr - (wc - 1 - cx) / fx * zl;
    const float dxy = (hc - cy) / fy * zr - (hc - cy) / fy * zl;
    const float dxz = zr - zl;
    const float dyx = (wc - cx) / fx * zd - (wc - cx) / fx * zu;
    const float dyy = (hc + 1 - cy) / fy * zd - (hc - 1 - cy) / fy * zu;
    const float dyz = zd - zu;

    float nx = dxy * dyz - dxz * dyy;
    float ny = dxz * dyx - dxx * dyz;
    float nz = dxx * dyy - dxy * dyx;
    const float nn = fmaxf(sqrtf(nx * nx + ny * ny + nz * nz), 1e-6f);
    const float sc = (1.0f - uncert) / nn;

    const float rx = ((float)w - cx) / fx;
    const float ry = ((float)h - cy) / fy;
    const float rn = fmaxf(sqrtf(rx * rx + ry * ry + 1.0f), 1e-12f);

    qin_s[128] = rx / rn;
    qin_s[129] = ry / rn;
    qin_s[130] = 1.0f / rn;
    qin_s[131] = nx * sc;
    qin_s[132] = ny * sc;
    qin_s[133] = nz * sc;
    qin_s[134] = uncert;
  }
  __syncthreads();

  // ---- q MLP (coalesced weight reads) ----
  float acc = bq1[t];
#pragma unroll 5
  for (int i = 0; i < QIN; ++i) acc += qin_s[i] * Wq1[i * HID + t];
  hs[t] = fmaxf(acc, 0.0f);
  __syncthreads();

  acc = bq2[t];
#pragma unroll 8
  for (int k = 0; k < HID; ++k) acc += hs[k] * Wq2[k * HID + t];
  qs[t] = fmaxf(acc, 0.0f);
  __syncthreads();

  // ---- logits vs all V anchors via transposed aT (lane-consecutive reads) ----
  const int col2 = 256 + (t < 44 ? t : 43);
  float d0 = 0.0f, d1 = 0.0f, d2 = 0.0f;
#pragma unroll 8
  for (int k = 0; k < HID; ++k) {
    const float qk = qs[k];
    const float* row = aT_ws + (size_t)k * V;
    d0 += qk * row[t];
    d1 += qk * row[t + 128];
    d2 += qk * row[col2];
  }
  const float rsq = 0.08838834764831845f;  // 1/sqrt(128)
  const float sc0 = 1.0f / (1.0f + expf(-(d0 * rsq + bias_ws[t])));
  const float sc1 = 1.0f / (1.0f + expf(-(d1 * rsq + bias_ws[t + 128])));
  const float sc2 = 1.0f / (1.0f + expf(-(d2 * rsq + bias_ws[col2])));

  float* vs_out = out_view_score + (size_t)bm * V;
  vs_out[t] = sc0;
  vs_out[t + 128] = sc1;
  if (t < 44) vs_out[t + 256] = sc2;

  // per-thread best in ascending-v order (first-index tie break)
  float bv = sc0; int bi = t;
  if (sc1 > bv) { bv = sc1; bi = t + 128; }
  if (t < 44 && sc2 > bv) { bv = sc2; bi = t + 256; }
#pragma unroll
  for (int o = 32; o > 0; o >>= 1) {
    const float ov = __shfl_down(bv, o, 64);
    const int oi = __shfl_down(bi, o, 64);
    if (ov > bv || (ov == bv && oi < bi)) { bv = ov; bi = oi; }
  }
  if (lane == 0) { wbv[wv] = bv; wbi[wv] = bi; }
  __syncthreads();

  if (t == 0) {
    float fbv = wbv[0]; int fbi = wbi[0];
    if (wbv[1] > fbv || (wbv[1] == fbv && wbi[1] < fbi)) { fbv = wbv[1]; fbi = wbi[1]; }
    sbest = fbi;

    out_top_inds[bm] = (float)fbi;
    const float vx = view_dirs[fbi * 3 + 0];
    const float vy = view_dirs[fbi * 3 + 1];
    const float vz = view_dirs[fbi * 3 + 2];
    out_top_xyz[(size_t)bm * 3 + 0] = vx;
    out_top_xyz[(size_t)bm * 3 + 1] = vy;
    out_top_xyz[(size_t)bm * 3 + 2] = vz;

    float ax0 = -vx, ax1 = -vy, ax2 = -vz;
    float ay0 = vy, ay1 = -vx, ay2 = 0.0f;
    const float nyn = sqrtf(ay0 * ay0 + ay1 * ay1);
    if (nyn < 1e-8f) {
      ay0 = 0.0f; ay1 = 1.0f; ay2 = 0.0f;
    } else {
      const float d = fmaxf(nyn, 1e-8f);
      ay0 /= d; ay1 /= d;
    }
    const float an = fmaxf(sqrtf(ax0 * ax0 + ax1 * ax1 + ax2 * ax2), 1e-8f);
    ax0 /= an; ax1 /= an; ax2 /= an;
    const float az0 = ax1 * ay2 - ax2 * ay1;
    const float az1 = ax2 * ay0 - ax0 * ay2;
    const float az2 = ax0 * ay1 - ax1 * ay0;
    float* R = out_rot + (size_t)bm * 9;
    R[0] = ax0; R[1] = ay0; R[2] = az0;
    R[3] = ax1; R[4] = ay1; R[5] = az1;
    R[6] = ax2; R[7] = ay2; R[8] = az2;
  }
  __syncthreads();
  const int best = sbest;

  // ---- residual MLP ----
  atop_s[t] = a_ws[best * HID + t];
  __syncthreads();

  float racc = br1[t];
#pragma unroll 8
  for (int k = 0; k < HID; ++k) racc += (qs[k] + atop_s[k]) * Wr1[k * HID + t];
  hs[t] = fmaxf(racc, 0.0f);
  __syncthreads();

  racc = br2[t];
#pragma unroll 8
  for (int k = 0; k < HID; ++k) racc += hs[k] * Wr2[k * HID + t];
  out_res[((size_t)b * C + t) * M + m] = racc;
}

// ---------------------------------------------------------------------------
extern "C" void kernel_launch(void* const* d_in, const int* in_sizes, int n_in,
                              void* d_out, int out_size, void* d_ws, size_t ws_size,
                              hipStream_t stream) {
  const float* seed  = (const float*)d_in[0];
  const int*   tok   = (const int*)d_in[1];
  const float* Km    = (const float*)d_in[2];
  const float* dmap  = (const float*)d_in[3];
  const float* dprob = (const float*)d_in[4];
  const float* vdirs = (const float*)d_in[5];
  const float* Wq1 = (const float*)d_in[6];  const float* bq1 = (const float*)d_in[7];
  const float* Wq2 = (const float*)d_in[8];  const float* bq2 = (const float*)d_in[9];
  const float* Wa1 = (const float*)d_in[10]; const float* ba1 = (const float*)d_in[11];
  const float* Wa2 = (const float*)d_in[12]; const float* ba2 = (const float*)d_in[13];
  const float* Wb1 = (const float*)d_in[14]; const float* bb1 = (const float*)d_in[15];
  const float* Wb2 = (const float*)d_in[16]; const float* bb2 = (const float*)d_in[17];
  const float* Wr1 = (const float*)d_in[18]; const float* br1 = (const float*)d_in[19];
  const float* Wr2 = (const float*)d_in[20]; const float* br2 = (const float*)d_in[21];

  float* out = (float*)d_out;
  float* vs  = out;                                  // view_score (B,M,V)
  float* ti  = vs + (size_t)B * M * V;               // top_inds  (B,M)
  float* tx  = ti + (size_t)B * M;                   // top_xyz   (B,M,3)
  float* rot = tx + (size_t)B * M * 3;               // rot       (B,M,3,3)
  float* rf  = rot + (size_t)B * M * 9;              // res_feat  (B,C,M)

  float* a_ws    = (float*)d_ws;                     // V*HID
  float* aT_ws   = a_ws + (size_t)V * HID;           // HID*V
  float* bias_ws = aT_ws + (size_t)HID * V;          // V
  float* seedT   = bias_ws + V;                      // B*M*C

  transpose_seed<<<dim3(C / 32, M / 32, B), dim3(32, 4), 0, stream>>>(seed, seedT);
  anchor_kernel<<<V, HID, 0, stream>>>(vdirs, Wa1, ba1, Wa2, ba2, Wb1, bb1, Wb2, bb2,
                                       a_ws, aT_ws, bias_ws);
  seed_kernel<<<B * M, 128, 0, stream>>>(seedT, tok, Km, dmap, dprob, vdirs,
                                         Wq1, bq1, Wq2, bq2, Wr1, br1, Wr2, br2,
                                         a_ws, aT_ws, bias_ws, vs, ti, tx, rot, rf);
}